// Round 4
// baseline (6624.050 us; speedup 1.0000x reference)
//
#include <hip/hip_runtime.h>
#include <hip/hip_bf16.h>

typedef unsigned short u16;
typedef unsigned int u32;
typedef unsigned long long u64;
typedef signed char i8;
using bf16x8 = __attribute__((ext_vector_type(8))) short;
using f32x4  = __attribute__((ext_vector_type(4))) float;
using i32x4  = __attribute__((ext_vector_type(4))) int;

__device__ inline u16 f2bf(float f) {
  union { float f; unsigned u; } v; v.f = f;
  unsigned u = v.u;
  unsigned r = (u + 0x7FFFu + ((u >> 16) & 1u)) >> 16;
  return (u16)r;
}
__device__ inline float bf2f(u16 b) {
  union { unsigned u; float f; } v; v.u = ((unsigned)b) << 16;
  return v.f;
}
__device__ inline float sigf(float x) { return 1.0f / (1.0f + __expf(-x)); }
__device__ inline float tanhfast(float x) { return 1.0f - 2.0f / (__expf(2.0f * x) + 1.0f); }

// ---------------- prep kernels ----------------

__global__ void cvt_bf16(const float* __restrict__ in, u16* __restrict__ out, int n) {
  for (int i = blockIdx.x * 256 + threadIdx.x; i < n; i += gridDim.x * 256)
    out[i] = f2bf(in[i]);
}

// G[j][c] = sum_i fc2w[i*256+j] * Avec[i][c]
__global__ __launch_bounds__(256) void gmat_kernel(const float* __restrict__ fc2w,
                                                   const float* __restrict__ dw,
                                                   float* __restrict__ G) {
  int j = threadIdx.x;
  float g0 = 0.f, g1 = 0.f, g2 = 0.f;
  for (int i = 0; i < 256; ++i) {
    float a0 = dw[i * 9 + 7] - dw[i * 9 + 5];
    float a1 = dw[i * 9 + 2] - dw[i * 9 + 6];
    float a2 = dw[i * 9 + 3] - dw[i * 9 + 1];
    float w = fc2w[i * 256 + j];
    g0 += w * a0; g1 += w * a1; g2 += w * a2;
  }
  G[j * 3 + 0] = g0; G[j * 3 + 1] = g1; G[j * 3 + 2] = g2;
}

// W_hh [1024][256] fp32 -> i8 with per-row scale sWq[row] = rowmax/127
__global__ __launch_bounds__(256) void quant_whh(const float* __restrict__ W,
                                                 i8* __restrict__ Wq,
                                                 float* __restrict__ sWq) {
  int w = threadIdx.x >> 6, lane = threadIdx.x & 63;
  int row = blockIdx.x * 4 + w;
  float4 v = *(const float4*)(W + (size_t)row * 256 + lane * 4);
  float m = fmaxf(fmaxf(fabsf(v.x), fabsf(v.y)), fmaxf(fabsf(v.z), fabsf(v.w)));
#pragma unroll
  for (int off = 1; off < 64; off <<= 1) m = fmaxf(m, __shfl_xor(m, off));
  float inv = m > 0.f ? 127.f / m : 0.f;
  int q0 = __float2int_rn(v.x * inv), q1 = __float2int_rn(v.y * inv);
  int q2 = __float2int_rn(v.z * inv), q3 = __float2int_rn(v.w * inv);
  u32 pk = (q0 & 255) | ((q1 & 255) << 8) | ((q2 & 255) << 16) | ((q3 & 255) << 24);
  *(u32*)(Wq + (size_t)row * 256 + lane * 4) = pk;
  if (lane == 0) sWq[row] = m * (1.f / 127.f);
}

// XG bf16 [rows][1024] -> i8 with per-row scale
__global__ __launch_bounds__(256) void xquant(const u16* __restrict__ Xb,
                                              i8* __restrict__ Xq,
                                              float* __restrict__ Xs) {
  int w = threadIdx.x >> 6, lane = threadIdx.x & 63;
  size_t row = (size_t)blockIdx.x * 4 + w;
  const u16* src = Xb + row * 1024 + lane * 16;
  bf16x8 a = *(const bf16x8*)src;
  bf16x8 b = *(const bf16x8*)(src + 8);
  float f[16];
#pragma unroll
  for (int e = 0; e < 8; ++e) { f[e] = bf2f((u16)a[e]); f[8 + e] = bf2f((u16)b[e]); }
  float m = 0.f;
#pragma unroll
  for (int e = 0; e < 16; ++e) m = fmaxf(m, fabsf(f[e]));
#pragma unroll
  for (int off = 1; off < 64; off <<= 1) m = fmaxf(m, __shfl_xor(m, off));
  float inv = m > 0.f ? 127.f / m : 0.f;
  u32 pk[4];
#pragma unroll
  for (int q = 0; q < 4; ++q) {
    int q0 = __float2int_rn(f[4 * q + 0] * inv), q1 = __float2int_rn(f[4 * q + 1] * inv);
    int q2 = __float2int_rn(f[4 * q + 2] * inv), q3 = __float2int_rn(f[4 * q + 3] * inv);
    pk[q] = (q0 & 255) | ((q1 & 255) << 8) | ((q2 & 255) << 16) | ((q3 & 255) << 24);
  }
  *(uint4*)(Xq + row * 1024 + lane * 16) = make_uint4(pk[0], pk[1], pk[2], pk[3]);
  if (lane == 0) Xs[row] = m * (1.f / 127.f);
}

// ---------------- fc1_1 (chunked over T) ----------------

__global__ __launch_bounds__(256) void fc1_kernel(const float* __restrict__ X,
                                                  const float* __restrict__ W1,
                                                  const float* __restrict__ b1,
                                                  u16* __restrict__ H1, int t0, int tcl2) {
  __shared__ float w1s[256 * 9];
  int tid = threadIdx.x;
  for (int idx = tid; idx < 2048; idx += 256)
    w1s[(idx >> 3) * 9 + (idx & 7)] = W1[idx];
  __syncthreads();
  float wreg[8];
#pragma unroll
  for (int i = 0; i < 8; ++i) wreg[i] = w1s[tid * 9 + i];
  float bb = b1[tid];
  int Tc = 1 << tcl2;
  int row0 = blockIdx.x * 64;
  for (int r = 0; r < 64; ++r) {
    int rl = row0 + r;
    int b = rl >> tcl2, tp = rl & (Tc - 1);
    const float4* xr = (const float4*)(X + ((size_t)b * 2048 + t0 + tp) * 8);
    float4 xa = xr[0], xb = xr[1];
    float acc = bb + xa.x * wreg[0] + xa.y * wreg[1] + xa.z * wreg[2] + xa.w * wreg[3]
                   + xb.x * wreg[4] + xb.y * wreg[5] + xb.z * wreg[6] + xb.w * wreg[7];
    H1[(size_t)rl * 256 + tid] = f2bf(fmaxf(acc, 0.f));
  }
}

// ---------------- bf16 MFMA GEMM, K=256 ----------------

__global__ __launch_bounds__(256) void gemm_k256(const u16* __restrict__ A,
                                                 const u16* __restrict__ Bw,
                                                 const float* __restrict__ bias0,
                                                 const float* __restrict__ bias1,
                                                 u16* __restrict__ out, int N, int relu) {
  int tid = threadIdx.x;
  int lane = tid & 63, wv = tid >> 6;
  int lr = lane & 15, lk = lane >> 4;
  int nblk = N >> 6;
  int mb = blockIdx.x / nblk, nb = blockIdx.x - mb * nblk;
  int R0 = mb * 128 + (wv >> 1) * 64;
  int C0 = nb * 64 + (wv & 1) * 32;
  f32x4 acc[4][2];
#pragma unroll
  for (int mt = 0; mt < 4; ++mt)
#pragma unroll
    for (int nt = 0; nt < 2; ++nt) acc[mt][nt] = (f32x4){0.f, 0.f, 0.f, 0.f};
#pragma unroll
  for (int kk = 0; kk < 8; ++kk) {
    int ko = 32 * kk + 8 * lk;
    bf16x8 af[4], bfr[2];
#pragma unroll
    for (int mt = 0; mt < 4; ++mt)
      af[mt] = *(const bf16x8*)(A + (size_t)(R0 + 16 * mt + lr) * 256 + ko);
#pragma unroll
    for (int nt = 0; nt < 2; ++nt)
      bfr[nt] = *(const bf16x8*)(Bw + (size_t)(C0 + 16 * nt + lr) * 256 + ko);
#pragma unroll
    for (int mt = 0; mt < 4; ++mt)
#pragma unroll
      for (int nt = 0; nt < 2; ++nt)
        acc[mt][nt] = __builtin_amdgcn_mfma_f32_16x16x32_bf16(af[mt], bfr[nt], acc[mt][nt], 0, 0, 0);
  }
#pragma unroll
  for (int nt = 0; nt < 2; ++nt) {
    int col = C0 + 16 * nt + lr;
    float bs = bias0[col] + (bias1 ? bias1[col] : 0.f);
#pragma unroll
    for (int mt = 0; mt < 4; ++mt) {
#pragma unroll
      for (int r = 0; r < 4; ++r) {
        int row = R0 + 16 * mt + 4 * lk + r;
        float v = acc[mt][nt][r] + bs;
        if (relu) v = fmaxf(v, 0.f);
        out[(size_t)row * N + col] = f2bf(v);
      }
    }
  }
}

// ---------------- persistent LSTM: one block per group, no exchange ----------------
// 8 blocks x 1024 threads. Block = group of 8 batches, holds the FULL W_hh as
// i8 MFMA B-fragments in VGPRs (64/lane). Per step: i8 MFMA (K=256) -> dequant
// gates -> fp32 cell update -> h re-quantized to i8 in LDS. x-preacts read as
// i8 (per-row scale), staged via LDS double-buffer. 2 barriers/step, no
// inter-block traffic at all.
__global__ __launch_bounds__(1024, 1) void lstm_kernel(const i8* __restrict__ Xq,
                                                       const float* __restrict__ Xs,
                                                       const i8* __restrict__ Wq,
                                                       const float* __restrict__ sWq,
                                                       const float* __restrict__ G,
                                                       float* __restrict__ wpart,
                                                       float* __restrict__ cstate,
                                                       float* __restrict__ hstate,
                                                       int t0, int Tc) {
  __shared__ i8 h_i8[16][272];
  __shared__ float gates[8][1040];
  __shared__ float sWl[1024];
  __shared__ i8 xq[2][8][1028];
  __shared__ float scl[2][8];

  int tid = threadIdx.x;
  int w = tid >> 6, lane = tid & 63;
  int lr = lane & 15, lk = lane >> 4;
  int grp = blockIdx.x, B0 = grp * 8;

  // weight fragments: local col c = 64*w + 16*ct + lr (== global gate row),
  // k-bytes [64*kb + 16*lk, +16)
  i32x4 wf[4][4];
#pragma unroll
  for (int ct = 0; ct < 4; ++ct)
#pragma unroll
    for (int kb = 0; kb < 4; ++kb)
      wf[ct][kb] = *(const i32x4*)(Wq + (size_t)(64 * w + 16 * ct + lr) * 256 + 64 * kb + 16 * lk);
  sWl[tid] = sWq[tid] * (1.f / 127.f);
  for (int i = tid; i < 16 * 272; i += 1024) ((i8*)h_i8)[i] = 0;

  int bu = tid >> 7;    // update batch (0..7)
  int ju = tid & 127;   // hidden index of unit0; unit1 = ju + 128
  float cst0, cst1, hp0, hp1;
  if (t0 == 0) {
    cst0 = cst1 = hp0 = hp1 = 0.f;
  } else {
    size_t si = (size_t)(B0 + bu) * 256;
    cst0 = cstate[si + ju]; cst1 = cstate[si + ju + 128];
    hp0 = hstate[si + ju];  hp1 = hstate[si + ju + 128];
  }
  float G0a = G[ju * 3 + 0], G1a = G[ju * 3 + 1], G2a = G[ju * 3 + 2];
  float G0b = G[(ju + 128) * 3 + 0], G1b = G[(ju + 128) * 3 + 1], G2b = G[(ju + 128) * 3 + 2];
  __syncthreads();  // zero-fill done
  if (t0 > 0) {
    h_i8[bu][ju] = (i8)__float2int_rn(hp0 * 127.f);
    h_i8[bu][ju + 128] = (i8)__float2int_rn(hp1 * 127.f);
  }

  // x staging pointers: word s=0 covers batches 0-3, s=1 batches 4-7
  int sb0 = tid >> 8, sc4 = (tid & 255) * 4;
  const i8* xb0 = Xq + ((size_t)(B0 + sb0) * Tc + t0 - t0) * 1024 + (size_t)0;  // base below
  xb0 = Xq + (size_t)(B0 + sb0) * Tc * 1024 + sc4;
  const i8* xb1 = Xq + (size_t)(B0 + 4 + sb0) * Tc * 1024 + sc4;
  // prologue: stage tp=0
  {
    u32 x0 = *(const u32*)xb0, x1 = *(const u32*)xb1;
    *(u32*)&xq[0][sb0][sc4] = x0;
    *(u32*)&xq[0][4 + sb0][sc4] = x1;
    if (tid < 8) scl[0][tid] = Xs[(size_t)(B0 + tid) * Tc];
  }
  __syncthreads();

  float* wp = wpart + ((size_t)(w & 1) * 64 + B0 + (w >> 1)) * 2047 * 3;
  if (t0 > 0) wp += (size_t)(t0 - 1) * 3;

  for (int tp = 0; tp < Tc; ++tp) {
    int t = t0 + tp;
    int buf = tp & 1;
    bool pf = (tp + 1 < Tc);
    u32 nx0 = 0, nx1 = 0;
    float ns = 0.f;
    if (pf) {
      xb0 += 1024; xb1 += 1024;
      nx0 = *(const u32*)xb0; nx1 = *(const u32*)xb1;
      if (tid < 8) ns = Xs[(size_t)(B0 + tid) * Tc + tp + 1];
    }
    // MFMA: gates_i32[b][c] = sum_k h_i8[b][k] * Wq[c][k]
    i32x4 acc[4];
#pragma unroll
    for (int ct = 0; ct < 4; ++ct) acc[ct] = (i32x4){0, 0, 0, 0};
#pragma unroll
    for (int kb = 0; kb < 4; ++kb) {
      i32x4 af = *(const i32x4*)&h_i8[lr][64 * kb + 16 * lk];
#pragma unroll
      for (int ct = 0; ct < 4; ++ct)
        acc[ct] = __builtin_amdgcn_mfma_i32_16x16x64_i8(af, wf[ct][kb], acc[ct], 0, 0, 0);
    }
    if (lk < 2) {
#pragma unroll
      for (int ct = 0; ct < 4; ++ct) {
        int c = 64 * w + 16 * ct + lr;
        float fs = sWl[c];
#pragma unroll
        for (int r = 0; r < 4; ++r) gates[4 * lk + r][c] = (float)acc[ct][r] * fs;
      }
    }
    __syncthreads();
    // update
    float sx = scl[buf][bu];
    float x0 = (float)xq[buf][bu][0 * 256 + ju] * sx + gates[bu][0 * 256 + ju];
    float x1 = (float)xq[buf][bu][1 * 256 + ju] * sx + gates[bu][1 * 256 + ju];
    float x2 = (float)xq[buf][bu][2 * 256 + ju] * sx + gates[bu][2 * 256 + ju];
    float x3 = (float)xq[buf][bu][3 * 256 + ju] * sx + gates[bu][3 * 256 + ju];
    float y0 = (float)xq[buf][bu][0 * 256 + ju + 128] * sx + gates[bu][0 * 256 + ju + 128];
    float y1 = (float)xq[buf][bu][1 * 256 + ju + 128] * sx + gates[bu][1 * 256 + ju + 128];
    float y2 = (float)xq[buf][bu][2 * 256 + ju + 128] * sx + gates[bu][2 * 256 + ju + 128];
    float y3 = (float)xq[buf][bu][3 * 256 + ju + 128] * sx + gates[bu][3 * 256 + ju + 128];
    cst0 = sigf(x1) * cst0 + sigf(x0) * tanhfast(x2);
    float hn0 = sigf(x3) * tanhfast(cst0);
    cst1 = sigf(y1) * cst1 + sigf(y0) * tanhfast(y2);
    float hn1 = sigf(y3) * tanhfast(cst1);
    float d0 = hn0 - hp0; hp0 = hn0;
    float d1 = hn1 - hp1; hp1 = hn1;
    h_i8[bu][ju] = (i8)__float2int_rn(hn0 * 127.f);
    h_i8[bu][ju + 128] = (i8)__float2int_rn(hn1 * 127.f);
    float wa0 = d0 * G0a + d1 * G0b;
    float wa1 = d0 * G1a + d1 * G1b;
    float wa2 = d0 * G2a + d1 * G2b;
#pragma unroll
    for (int off = 1; off < 64; off <<= 1) {
      wa0 += __shfl_xor(wa0, off);
      wa1 += __shfl_xor(wa1, off);
      wa2 += __shfl_xor(wa2, off);
    }
    if (lane == 0 && t >= 1) { wp[0] = wa0; wp[1] = wa1; wp[2] = wa2; }
    if (t >= 1) wp += 3;
    if (pf) {
      *(u32*)&xq[buf ^ 1][sb0][sc4] = nx0;
      *(u32*)&xq[buf ^ 1][4 + sb0][sc4] = nx1;
      if (tid < 8) scl[buf ^ 1][tid] = ns;
    }
    __syncthreads();
  }
  {
    size_t si = (size_t)(B0 + bu) * 256;
    cstate[si + ju] = cst0; cstate[si + ju + 128] = cst1;
    hstate[si + ju] = hp0;  hstate[si + ju + 128] = hp1;
  }
}

// ---------------- rotation prefix scan ----------------

__device__ inline void mat3mul(float* __restrict__ o, const float* a, const float* b) {
#pragma unroll
  for (int i = 0; i < 3; ++i)
#pragma unroll
    for (int j = 0; j < 3; ++j)
      o[i * 3 + j] = a[i * 3 + 0] * b[0 * 3 + j] + a[i * 3 + 1] * b[1 * 3 + j] + a[i * 3 + 2] * b[2 * 3 + j];
}

__device__ inline void rodrigues(float w1, float w2, float w3, float* R) {
  float t2 = w1 * w1 + w2 * w2 + w3 * w3;
  float A, Bc;
  if (t2 < 1e-8f) {
    A = 1.f - t2 * (1.f / 6.f);
    Bc = 0.5f - t2 * (1.f / 24.f);
  } else {
    float th = sqrtf(t2);
    A = __sinf(th) / th;
    Bc = (1.f - __cosf(th)) / t2;
  }
  float c_ = 1.f - Bc * t2;
  R[0] = c_ + Bc * w1 * w1; R[1] = Bc * w1 * w2 - A * w3; R[2] = Bc * w1 * w3 + A * w2;
  R[3] = Bc * w1 * w2 + A * w3; R[4] = c_ + Bc * w2 * w2; R[5] = Bc * w2 * w3 - A * w1;
  R[6] = Bc * w1 * w3 - A * w2; R[7] = Bc * w2 * w3 + A * w1; R[8] = c_ + Bc * w3 * w3;
}

__global__ __launch_bounds__(256) void rotscan_kernel(const float* __restrict__ wpart,
                                                      float* __restrict__ out) {
  __shared__ float buf[2][256][9];
  int b = blockIdx.x, tid = threadIdx.x;
  const float* w0 = wpart + ((size_t)0 * 64 + b) * 2047 * 3;
  const float* w1 = wpart + ((size_t)1 * 64 + b) * 2047 * 3;
  float R[8][9];
  float C[9] = {1, 0, 0, 0, 1, 0, 0, 0, 1};
#pragma unroll
  for (int s = 0; s < 8; ++s) {
    int idx = tid * 8 + s;
    float wx = 0.f, wy = 0.f, wz = 0.f;
    if (idx < 2047) {
      wx = w0[idx * 3 + 0] + w1[idx * 3 + 0];
      wy = w0[idx * 3 + 1] + w1[idx * 3 + 1];
      wz = w0[idx * 3 + 2] + w1[idx * 3 + 2];
    }
    rodrigues(wx, wy, wz, R[s]);
    float T_[9];
    mat3mul(T_, C, R[s]);
#pragma unroll
    for (int e = 0; e < 9; ++e) C[e] = T_[e];
  }
#pragma unroll
  for (int e = 0; e < 9; ++e) buf[0][tid][e] = C[e];
  __syncthreads();
  int p = 0;
  for (int d = 1; d < 256; d <<= 1) {
    float L[9];
    if (tid >= d) {
      mat3mul(L, buf[p][tid - d], buf[p][tid]);
    } else {
#pragma unroll
      for (int e = 0; e < 9; ++e) L[e] = buf[p][tid][e];
    }
#pragma unroll
    for (int e = 0; e < 9; ++e) buf[p ^ 1][tid][e] = L[e];
    __syncthreads();
    p ^= 1;
  }
  float P[9];
  if (tid == 0) {
    P[0] = 1; P[1] = 0; P[2] = 0; P[3] = 0; P[4] = 1; P[5] = 0; P[6] = 0; P[7] = 0; P[8] = 1;
  } else {
#pragma unroll
    for (int e = 0; e < 9; ++e) P[e] = buf[p][tid - 1][e];
  }
#pragma unroll
  for (int s = 0; s < 8; ++s) {
    float Q[9];
    mat3mul(Q, P, R[s]);
#pragma unroll
    for (int e = 0; e < 9; ++e) P[e] = Q[e];
    int idx = tid * 8 + s;
    if (idx < 2047) {
      size_t o = ((size_t)b * 2047 + idx) * 3;
      out[o + 0] = P[2]; out[o + 1] = P[5]; out[o + 2] = P[8];
    }
  }
}

// ---------------- launch ----------------

extern "C" void kernel_launch(void* const* d_in, const int* in_sizes, int n_in,
                              void* d_out, int out_size, void* d_ws, size_t ws_size,
                              hipStream_t stream) {
  const float* X    = (const float*)d_in[0];
  const float* w1   = (const float*)d_in[1];
  const float* b1   = (const float*)d_in[2];
  const float* w2   = (const float*)d_in[3];
  const float* b2   = (const float*)d_in[4];
  const float* Wih  = (const float*)d_in[5];
  const float* Whh  = (const float*)d_in[6];
  const float* bih  = (const float*)d_in[7];
  const float* bhh  = (const float*)d_in[8];
  const float* fc2w = (const float*)d_in[9];
  const float* devw = (const float*)d_in[11];
  float* out = (float*)d_out;

  char* ws = (char*)d_ws;
  size_t off = 0;
  auto take = [&](size_t bytes) { size_t p = off; off = (off + bytes + 255) & ~255ULL; return p; };
  size_t oW2b   = take((size_t)256 * 256 * 2);
  size_t oWIHb  = take((size_t)1024 * 256 * 2);
  size_t oWq    = take((size_t)1024 * 256);
  size_t osWq   = take((size_t)1024 * 4);
  size_t oG     = take((size_t)256 * 3 * 4);
  size_t oWPART = take((size_t)2 * 64 * 2047 * 3 * 4);
  size_t oCST   = take((size_t)64 * 256 * 4);
  size_t oHST   = take((size_t)64 * 256 * 4);
  size_t fixed = off;

  // per-t chunk bytes: H1 32768 + Y2 32768 + XGb 131072 + XQ 65536 + XS 256
  int Tc = 2048, tcl2 = 11;
  while (Tc > 2 && fixed + (size_t)Tc * 262400 + 4096 > ws_size) { Tc >>= 1; --tcl2; }
  if (fixed + (size_t)Tc * 262400 + 4096 > ws_size) return;

  size_t oH1  = take((size_t)64 * Tc * 256 * 2);
  size_t oY2  = take((size_t)64 * Tc * 256 * 2);
  size_t oXGb = take((size_t)64 * Tc * 1024 * 2);
  size_t oXQ  = take((size_t)64 * Tc * 1024);
  size_t oXS  = take((size_t)64 * Tc * 4);

  u16* W2b     = (u16*)(ws + oW2b);
  u16* WIHb    = (u16*)(ws + oWIHb);
  i8* Wq       = (i8*)(ws + oWq);
  float* sWq   = (float*)(ws + osWq);
  float* G     = (float*)(ws + oG);
  float* WPART = (float*)(ws + oWPART);
  float* CST   = (float*)(ws + oCST);
  float* HST   = (float*)(ws + oHST);
  u16* H1      = (u16*)(ws + oH1);
  u16* Y2      = (u16*)(ws + oY2);
  u16* XGb     = (u16*)(ws + oXGb);
  i8* XQ       = (i8*)(ws + oXQ);
  float* XS    = (float*)(ws + oXS);

  cvt_bf16<<<dim3(64), dim3(256), 0, stream>>>(w2, W2b, 256 * 256);
  cvt_bf16<<<dim3(256), dim3(256), 0, stream>>>(Wih, WIHb, 1024 * 256);
  quant_whh<<<dim3(256), dim3(256), 0, stream>>>(Whh, Wq, sWq);
  gmat_kernel<<<dim3(1), dim3(256), 0, stream>>>(fc2w, devw, G);

  int NC = 2048 / Tc;
  int mb = (64 * Tc) / 128;
  for (int c = 0; c < NC; ++c) {
    int t0 = c * Tc;
    fc1_kernel<<<dim3(Tc), dim3(256), 0, stream>>>(X, w1, b1, H1, t0, tcl2);
    gemm_k256<<<dim3(mb * 4), dim3(256), 0, stream>>>(H1, W2b, b2, (const float*)nullptr, Y2, 256, 1);
    gemm_k256<<<dim3(mb * 16), dim3(256), 0, stream>>>(Y2, WIHb, bih, bhh, XGb, 1024, 0);
    xquant<<<dim3(16 * Tc), dim3(256), 0, stream>>>(XGb, XQ, XS);
    lstm_kernel<<<dim3(8), dim3(1024), 0, stream>>>(XQ, XS, Wq, sWq, G, WPART, CST, HST, t0, Tc);
  }
  rotscan_kernel<<<dim3(64), dim3(256), 0, stream>>>(WPART, out);
}

// Round 5
// 2611.044 us; speedup vs baseline: 2.5369x; 2.5369x over previous
//
#include <hip/hip_runtime.h>
#include <hip/hip_bf16.h>

typedef unsigned short u16;
typedef unsigned int u32;
typedef unsigned long long u64;
typedef signed char i8;
using bf16x8 = __attribute__((ext_vector_type(8))) short;
using f32x4  = __attribute__((ext_vector_type(4))) float;
using i32x4  = __attribute__((ext_vector_type(4))) int;

__device__ inline u16 f2bf(float f) {
  union { float f; unsigned u; } v; v.f = f;
  unsigned u = v.u;
  unsigned r = (u + 0x7FFFu + ((u >> 16) & 1u)) >> 16;
  return (u16)r;
}
__device__ inline float bf2f(u16 b) {
  union { unsigned u; float f; } v; v.u = ((unsigned)b) << 16;
  return v.f;
}
__device__ inline float sigf(float x) { return 1.0f / (1.0f + __expf(-x)); }
__device__ inline float tanhfast(float x) { return 1.0f - 2.0f / (__expf(2.0f * x) + 1.0f); }

// ---------------- prep kernels ----------------

__global__ void cvt_bf16(const float* __restrict__ in, u16* __restrict__ out, int n) {
  for (int i = blockIdx.x * 256 + threadIdx.x; i < n; i += gridDim.x * 256)
    out[i] = f2bf(in[i]);
}

// G[j][c] = sum_i fc2w[i*256+j] * Avec[i][c]
__global__ __launch_bounds__(256) void gmat_kernel(const float* __restrict__ fc2w,
                                                   const float* __restrict__ dw,
                                                   float* __restrict__ G) {
  int j = threadIdx.x;
  float g0 = 0.f, g1 = 0.f, g2 = 0.f;
  for (int i = 0; i < 256; ++i) {
    float a0 = dw[i * 9 + 7] - dw[i * 9 + 5];
    float a1 = dw[i * 9 + 2] - dw[i * 9 + 6];
    float a2 = dw[i * 9 + 3] - dw[i * 9 + 1];
    float w = fc2w[i * 256 + j];
    g0 += w * a0; g1 += w * a1; g2 += w * a2;
  }
  G[j * 3 + 0] = g0; G[j * 3 + 1] = g1; G[j * 3 + 2] = g2;
}

// W_hh [1024][256] fp32 -> i8 with per-row scale sWq[row] = rowmax/127
__global__ __launch_bounds__(256) void quant_whh(const float* __restrict__ W,
                                                 i8* __restrict__ Wq,
                                                 float* __restrict__ sWq) {
  int w = threadIdx.x >> 6, lane = threadIdx.x & 63;
  int row = blockIdx.x * 4 + w;
  float4 v = *(const float4*)(W + (size_t)row * 256 + lane * 4);
  float m = fmaxf(fmaxf(fabsf(v.x), fabsf(v.y)), fmaxf(fabsf(v.z), fabsf(v.w)));
#pragma unroll
  for (int off = 1; off < 64; off <<= 1) m = fmaxf(m, __shfl_xor(m, off));
  float inv = m > 0.f ? 127.f / m : 0.f;
  int q0 = __float2int_rn(v.x * inv), q1 = __float2int_rn(v.y * inv);
  int q2 = __float2int_rn(v.z * inv), q3 = __float2int_rn(v.w * inv);
  u32 pk = (q0 & 255) | ((q1 & 255) << 8) | ((q2 & 255) << 16) | ((q3 & 255) << 24);
  *(u32*)(Wq + (size_t)row * 256 + lane * 4) = pk;
  if (lane == 0) sWq[row] = m * (1.f / 127.f);
}

// ---------------- fc1_1 (chunked over T) ----------------

__global__ __launch_bounds__(256) void fc1_kernel(const float* __restrict__ X,
                                                  const float* __restrict__ W1,
                                                  const float* __restrict__ b1,
                                                  u16* __restrict__ H1, int t0, int tcl2) {
  __shared__ float w1s[256 * 9];
  int tid = threadIdx.x;
  for (int idx = tid; idx < 2048; idx += 256)
    w1s[(idx >> 3) * 9 + (idx & 7)] = W1[idx];
  __syncthreads();
  float wreg[8];
#pragma unroll
  for (int i = 0; i < 8; ++i) wreg[i] = w1s[tid * 9 + i];
  float bb = b1[tid];
  int Tc = 1 << tcl2;
  int row0 = blockIdx.x * 64;
  for (int r = 0; r < 64; ++r) {
    int rl = row0 + r;
    int b = rl >> tcl2, tp = rl & (Tc - 1);
    const float4* xr = (const float4*)(X + ((size_t)b * 2048 + t0 + tp) * 8);
    float4 xa = xr[0], xb = xr[1];
    float acc = bb + xa.x * wreg[0] + xa.y * wreg[1] + xa.z * wreg[2] + xa.w * wreg[3]
                   + xb.x * wreg[4] + xb.y * wreg[5] + xb.z * wreg[6] + xb.w * wreg[7];
    H1[(size_t)rl * 256 + tid] = f2bf(fmaxf(acc, 0.f));
  }
}

// ---------------- bf16 MFMA GEMM, K=256 ----------------

__global__ __launch_bounds__(256) void gemm_k256(const u16* __restrict__ A,
                                                 const u16* __restrict__ Bw,
                                                 const float* __restrict__ bias0,
                                                 const float* __restrict__ bias1,
                                                 u16* __restrict__ out, int N, int relu) {
  int tid = threadIdx.x;
  int lane = tid & 63, wv = tid >> 6;
  int lr = lane & 15, lk = lane >> 4;
  int nblk = N >> 6;
  int mb = blockIdx.x / nblk, nb = blockIdx.x - mb * nblk;
  int R0 = mb * 128 + (wv >> 1) * 64;
  int C0 = nb * 64 + (wv & 1) * 32;
  f32x4 acc[4][2];
#pragma unroll
  for (int mt = 0; mt < 4; ++mt)
#pragma unroll
    for (int nt = 0; nt < 2; ++nt) acc[mt][nt] = (f32x4){0.f, 0.f, 0.f, 0.f};
#pragma unroll
  for (int kk = 0; kk < 8; ++kk) {
    int ko = 32 * kk + 8 * lk;
    bf16x8 af[4], bfr[2];
#pragma unroll
    for (int mt = 0; mt < 4; ++mt)
      af[mt] = *(const bf16x8*)(A + (size_t)(R0 + 16 * mt + lr) * 256 + ko);
#pragma unroll
    for (int nt = 0; nt < 2; ++nt)
      bfr[nt] = *(const bf16x8*)(Bw + (size_t)(C0 + 16 * nt + lr) * 256 + ko);
#pragma unroll
    for (int mt = 0; mt < 4; ++mt)
#pragma unroll
      for (int nt = 0; nt < 2; ++nt)
        acc[mt][nt] = __builtin_amdgcn_mfma_f32_16x16x32_bf16(af[mt], bfr[nt], acc[mt][nt], 0, 0, 0);
  }
#pragma unroll
  for (int nt = 0; nt < 2; ++nt) {
    int col = C0 + 16 * nt + lr;
    float bs = bias0[col] + (bias1 ? bias1[col] : 0.f);
#pragma unroll
    for (int mt = 0; mt < 4; ++mt) {
#pragma unroll
      for (int r = 0; r < 4; ++r) {
        int row = R0 + 16 * mt + 4 * lk + r;
        float v = acc[mt][nt][r] + bs;
        if (relu) v = fmaxf(v, 0.f);
        out[(size_t)row * N + col] = f2bf(v);
      }
    }
  }
}

// ---------------- persistent LSTM: 1 batch per block, W_hh fully in VGPRs ----
// 64 blocks x 512 thr (8 waves). Each block owns one batch; full i8 W_hh
// (256 KB) lives in VGPRs (128/lane). A-operand = broadcast h (all 16 M-rows
// identical -> C rows identical; dequant from row 0). Waves 0-3 do the cell
// update (1 unit/thread); waves 4-7 prefetch next-step bf16 gate preacts.
// No inter-block communication, no atomics. d = h_t - h_{t-1} stored fp32.
__global__ __launch_bounds__(512, 2) void lstm_kernel(const u16* __restrict__ XGb,
                                                      const i8* __restrict__ Wq,
                                                      const float* __restrict__ sWq,
                                                      float* __restrict__ dbuf,
                                                      float* __restrict__ cstate,
                                                      float* __restrict__ hstate,
                                                      int t0, int Tc) {
  __shared__ i8 h_i8[288];
  __shared__ float gates[1056];
  __shared__ u16 xstage[2][1056];

  int tid = threadIdx.x;
  int w = tid >> 6, lane = tid & 63;
  int lr = lane & 15, lk = lane >> 4;
  int b = blockIdx.x;

  // weight fragments: wave w owns gate-cols [128w, 128w+128)
  i32x4 wf[8][4];
  float swf[8];
#pragma unroll
  for (int ct = 0; ct < 8; ++ct) {
    int col = 128 * w + 16 * ct + lr;
#pragma unroll
    for (int kb = 0; kb < 4; ++kb)
      wf[ct][kb] = *(const i32x4*)(Wq + (size_t)col * 256 + 64 * kb + 16 * lk);
    swf[ct] = sWq[col] * (1.f / 127.f);
  }

  int j = 64 * w + lane;  // updater's hidden unit (valid for w<4)
  float cst = 0.f, hp = 0.f;
  if (w < 4) {
    if (t0 > 0) {
      cst = cstate[b * 256 + j];
      hp = hstate[b * 256 + j];
      h_i8[j] = (i8)__float2int_rn(hp * 127.f);
    } else {
      h_i8[j] = 0;
    }
  }
  int pidx = (w - 4) * 64 + lane;  // prefetcher slot (valid for w>=4)
  const u16* xpf = XGb + (size_t)b * Tc * 1024 + pidx * 4;
  if (w >= 4) {
    uint2 v = *(const uint2*)xpf;
    *(uint2*)&xstage[0][pidx * 4] = v;
  }
  float* dp = dbuf + (size_t)b * Tc * 256 + j;
  __syncthreads();

  for (int tp = 0; tp < Tc; ++tp) {
    int buf = tp & 1;
    uint2 nx;
    bool pf = (w >= 4) && (tp + 1 < Tc);
    if (pf) { xpf += 1024; nx = *(const uint2*)xpf; }
    // ---- MFMA phase: gates[c] = sum_k h[k] * W[c][k] (all 8 waves) ----
    i32x4 af[4];
#pragma unroll
    for (int kb = 0; kb < 4; ++kb)
      af[kb] = *(const i32x4*)&h_i8[64 * kb + 16 * lk];  // broadcast across lr
    i32x4 accs[8];
#pragma unroll
    for (int ct = 0; ct < 8; ++ct) {
      i32x4 a = (i32x4){0, 0, 0, 0};
#pragma unroll
      for (int kb = 0; kb < 4; ++kb)
        a = __builtin_amdgcn_mfma_i32_16x16x64_i8(af[kb], wf[ct][kb], a, 0, 0, 0);
      accs[ct] = a;
    }
    if (lk == 0) {  // row 0 of C; all rows identical (broadcast A)
#pragma unroll
      for (int ct = 0; ct < 8; ++ct)
        gates[128 * w + 16 * ct + lr] = (float)accs[ct][0] * swf[ct];
    }
    __syncthreads();
    // ---- update phase ----
    if (w < 4) {
      float pi = bf2f(xstage[buf][j]) + gates[j];
      float pf_ = bf2f(xstage[buf][256 + j]) + gates[256 + j];
      float pg = bf2f(xstage[buf][512 + j]) + gates[512 + j];
      float po = bf2f(xstage[buf][768 + j]) + gates[768 + j];
      cst = sigf(pf_) * cst + sigf(pi) * tanhfast(pg);
      float hn = sigf(po) * tanhfast(cst);
      float dd = hn - hp; hp = hn;
      h_i8[j] = (i8)__float2int_rn(hn * 127.f);
      dp[0] = dd;
      dp += 256;
    } else if (tp + 1 < Tc) {
      *(uint2*)&xstage[buf ^ 1][pidx * 4] = nx;
    }
    __syncthreads();
  }
  if (w < 4) {
    cstate[b * 256 + j] = cst;
    hstate[b * 256 + j] = hp;
  }
}

// ---------------- omega reduction: wpart[b][t-1][c] = sum_j d[b][t][j]*G[j][c]
__global__ __launch_bounds__(256) void wred_kernel(const float* __restrict__ dbuf,
                                                   const float* __restrict__ G,
                                                   float* __restrict__ wpart,
                                                   int t0, int Tc) {
  int b = blockIdx.x, tt = blockIdx.y;
  int tid = threadIdx.x, w = tid >> 6, lane = tid & 63;
  float Gr[4][3];
#pragma unroll
  for (int q = 0; q < 4; ++q)
#pragma unroll
    for (int c = 0; c < 3; ++c) Gr[q][c] = G[(q * 64 + lane) * 3 + c];
  for (int i = 0; i < 16; ++i) {
    int tp = tt * 64 + w * 16 + i;
    const float* dp = dbuf + ((size_t)b * Tc + tp) * 256;
    float d0 = dp[lane], d1 = dp[64 + lane], d2 = dp[128 + lane], d3 = dp[192 + lane];
    float p0 = d0 * Gr[0][0] + d1 * Gr[1][0] + d2 * Gr[2][0] + d3 * Gr[3][0];
    float p1 = d0 * Gr[0][1] + d1 * Gr[1][1] + d2 * Gr[2][1] + d3 * Gr[3][1];
    float p2 = d0 * Gr[0][2] + d1 * Gr[1][2] + d2 * Gr[2][2] + d3 * Gr[3][2];
#pragma unroll
    for (int off = 1; off < 64; off <<= 1) {
      p0 += __shfl_xor(p0, off);
      p1 += __shfl_xor(p1, off);
      p2 += __shfl_xor(p2, off);
    }
    int t = t0 + tp;
    if (lane == 0 && t >= 1) {
      size_t o = ((size_t)b * 2047 + (t - 1)) * 3;
      wpart[o + 0] = p0; wpart[o + 1] = p1; wpart[o + 2] = p2;
    }
  }
}

// ---------------- rotation prefix scan ----------------

__device__ inline void mat3mul(float* __restrict__ o, const float* a, const float* b) {
#pragma unroll
  for (int i = 0; i < 3; ++i)
#pragma unroll
    for (int j = 0; j < 3; ++j)
      o[i * 3 + j] = a[i * 3 + 0] * b[0 * 3 + j] + a[i * 3 + 1] * b[1 * 3 + j] + a[i * 3 + 2] * b[2 * 3 + j];
}

__device__ inline void rodrigues(float w1, float w2, float w3, float* R) {
  float t2 = w1 * w1 + w2 * w2 + w3 * w3;
  float A, Bc;
  if (t2 < 1e-8f) {
    A = 1.f - t2 * (1.f / 6.f);
    Bc = 0.5f - t2 * (1.f / 24.f);
  } else {
    float th = sqrtf(t2);
    A = __sinf(th) / th;
    Bc = (1.f - __cosf(th)) / t2;
  }
  float c_ = 1.f - Bc * t2;
  R[0] = c_ + Bc * w1 * w1; R[1] = Bc * w1 * w2 - A * w3; R[2] = Bc * w1 * w3 + A * w2;
  R[3] = Bc * w1 * w2 + A * w3; R[4] = c_ + Bc * w2 * w2; R[5] = Bc * w2 * w3 - A * w1;
  R[6] = Bc * w1 * w3 - A * w2; R[7] = Bc * w2 * w3 + A * w1; R[8] = c_ + Bc * w3 * w3;
}

__global__ __launch_bounds__(256) void rotscan_kernel(const float* __restrict__ wpart,
                                                      float* __restrict__ out) {
  __shared__ float buf[2][256][9];
  int b = blockIdx.x, tid = threadIdx.x;
  const float* w0 = wpart + (size_t)b * 2047 * 3;
  float R[8][9];
  float C[9] = {1, 0, 0, 0, 1, 0, 0, 0, 1};
#pragma unroll
  for (int s = 0; s < 8; ++s) {
    int idx = tid * 8 + s;
    float wx = 0.f, wy = 0.f, wz = 0.f;
    if (idx < 2047) {
      wx = w0[idx * 3 + 0];
      wy = w0[idx * 3 + 1];
      wz = w0[idx * 3 + 2];
    }
    rodrigues(wx, wy, wz, R[s]);
    float T_[9];
    mat3mul(T_, C, R[s]);
#pragma unroll
    for (int e = 0; e < 9; ++e) C[e] = T_[e];
  }
#pragma unroll
  for (int e = 0; e < 9; ++e) buf[0][tid][e] = C[e];
  __syncthreads();
  int p = 0;
  for (int d = 1; d < 256; d <<= 1) {
    float L[9];
    if (tid >= d) {
      mat3mul(L, buf[p][tid - d], buf[p][tid]);
    } else {
#pragma unroll
      for (int e = 0; e < 9; ++e) L[e] = buf[p][tid][e];
    }
#pragma unroll
    for (int e = 0; e < 9; ++e) buf[p ^ 1][tid][e] = L[e];
    __syncthreads();
    p ^= 1;
  }
  float P[9];
  if (tid == 0) {
    P[0] = 1; P[1] = 0; P[2] = 0; P[3] = 0; P[4] = 1; P[5] = 0; P[6] = 0; P[7] = 0; P[8] = 1;
  } else {
#pragma unroll
    for (int e = 0; e < 9; ++e) P[e] = buf[p][tid - 1][e];
  }
#pragma unroll
  for (int s = 0; s < 8; ++s) {
    float Q[9];
    mat3mul(Q, P, R[s]);
#pragma unroll
    for (int e = 0; e < 9; ++e) P[e] = Q[e];
    int idx = tid * 8 + s;
    if (idx < 2047) {
      size_t o = ((size_t)b * 2047 + idx) * 3;
      out[o + 0] = P[2]; out[o + 1] = P[5]; out[o + 2] = P[8];
    }
  }
}

// ---------------- launch ----------------

extern "C" void kernel_launch(void* const* d_in, const int* in_sizes, int n_in,
                              void* d_out, int out_size, void* d_ws, size_t ws_size,
                              hipStream_t stream) {
  const float* X    = (const float*)d_in[0];
  const float* w1   = (const float*)d_in[1];
  const float* b1   = (const float*)d_in[2];
  const float* w2   = (const float*)d_in[3];
  const float* b2   = (const float*)d_in[4];
  const float* Wih  = (const float*)d_in[5];
  const float* Whh  = (const float*)d_in[6];
  const float* bih  = (const float*)d_in[7];
  const float* bhh  = (const float*)d_in[8];
  const float* fc2w = (const float*)d_in[9];
  const float* devw = (const float*)d_in[11];
  float* out = (float*)d_out;

  char* ws = (char*)d_ws;
  size_t off = 0;
  auto take = [&](size_t bytes) { size_t p = off; off = (off + bytes + 255) & ~255ULL; return p; };
  size_t oW2b   = take((size_t)256 * 256 * 2);
  size_t oWIHb  = take((size_t)1024 * 256 * 2);
  size_t oWq    = take((size_t)1024 * 256);
  size_t osWq   = take((size_t)1024 * 4);
  size_t oG     = take((size_t)256 * 3 * 4);
  size_t oWPART = take((size_t)64 * 2047 * 3 * 4);
  size_t oCST   = take((size_t)64 * 256 * 4);
  size_t oHST   = take((size_t)64 * 256 * 4);
  size_t fixed = off;

  // per-t bytes: H1 32768 + Y2 32768 + XGb 131072 + D 65536 = 262144
  int Tc = 2048, tcl2 = 11;
  while (Tc > 64 && fixed + (size_t)Tc * 262144 + 4096 > ws_size) { Tc >>= 1; --tcl2; }
  if (fixed + (size_t)Tc * 262144 + 4096 > ws_size) return;

  size_t oH1  = take((size_t)64 * Tc * 256 * 2);
  size_t oY2  = take((size_t)64 * Tc * 256 * 2);
  size_t oXGb = take((size_t)64 * Tc * 1024 * 2);
  size_t oD   = take((size_t)64 * Tc * 256 * 4);

  u16* W2b     = (u16*)(ws + oW2b);
  u16* WIHb    = (u16*)(ws + oWIHb);
  i8* Wq       = (i8*)(ws + oWq);
  float* sWq   = (float*)(ws + osWq);
  float* G     = (float*)(ws + oG);
  float* WPART = (float*)(ws + oWPART);
  float* CST   = (float*)(ws + oCST);
  float* HST   = (float*)(ws + oHST);
  u16* H1      = (u16*)(ws + oH1);
  u16* Y2      = (u16*)(ws + oY2);
  u16* XGb     = (u16*)(ws + oXGb);
  float* D     = (float*)(ws + oD);

  cvt_bf16<<<dim3(64), dim3(256), 0, stream>>>(w2, W2b, 256 * 256);
  cvt_bf16<<<dim3(256), dim3(256), 0, stream>>>(Wih, WIHb, 1024 * 256);
  quant_whh<<<dim3(256), dim3(256), 0, stream>>>(Whh, Wq, sWq);
  gmat_kernel<<<dim3(1), dim3(256), 0, stream>>>(fc2w, devw, G);

  int NC = 2048 / Tc;
  int mb = (64 * Tc) / 128;
  for (int c = 0; c < NC; ++c) {
    int t0 = c * Tc;
    fc1_kernel<<<dim3(Tc), dim3(256), 0, stream>>>(X, w1, b1, H1, t0, tcl2);
    gemm_k256<<<dim3(mb * 4), dim3(256), 0, stream>>>(H1, W2b, b2, (const float*)nullptr, Y2, 256, 1);
    gemm_k256<<<dim3(mb * 16), dim3(256), 0, stream>>>(Y2, WIHb, bih, bhh, XGb, 1024, 0);
    lstm_kernel<<<dim3(64), dim3(512), 0, stream>>>(XGb, Wq, sWq, D, CST, HST, t0, Tc);
    wred_kernel<<<dim3(64, Tc / 64), dim3(256), 0, stream>>>(D, G, WPART, t0, Tc);
  }
  rotscan_kernel<<<dim3(64), dim3(256), 0, stream>>>(WPART, out);
}